// Round 3
// baseline (850.585 us; speedup 1.0000x reference)
//
#include <hip/hip_runtime.h>
#include <hip/hip_bf16.h>
#include <cstdint>
#include <cstddef>

typedef _Float16 f16_t;
typedef _Float16 h2    __attribute__((ext_vector_type(2)));
typedef _Float16 f16x8 __attribute__((ext_vector_type(8)));
typedef float    f32x4 __attribute__((ext_vector_type(4)));

#define MFMA_F16(A, Bv, Cv) __builtin_amdgcn_mfma_f32_16x16x32_f16((A), (Bv), (Cv), 0, 0, 0)

__device__ __forceinline__ float fdot2_(h2 a, h2 b, float c) {
#if __has_builtin(__builtin_amdgcn_fdot2)
  return __builtin_amdgcn_fdot2(a, b, c, false);
#else
  return c + (float)a[0] * (float)b[0] + (float)a[1] * (float)b[1];
#endif
}

// ---------------------------------------------------------------------------
// W fp32 -> f16 converters (run while target ws region is dead).
// ---------------------------------------------------------------------------
__global__ __launch_bounds__(256) void wconvA_kernel(
    const float* __restrict__ Wq, const float* __restrict__ Wk,
    const float* __restrict__ Wv, f16_t* __restrict__ dst)
{
  int idx = blockIdx.x * 256 + threadIdx.x;        // 98304 float4 tasks
  int src = idx >> 15, off = idx & 32767;
  const float* W = (src == 0) ? Wq : (src == 1) ? Wk : Wv;
  float4 a = *(const float4*)(W + (size_t)off * 4);
  f16_t* d = dst + (size_t)src * 131072 + (size_t)off * 4;
  d[0] = (f16_t)a.x; d[1] = (f16_t)a.y; d[2] = (f16_t)a.z; d[3] = (f16_t)a.w;
}

__global__ __launch_bounds__(256) void wconvB_kernel(
    const float* __restrict__ Wfc, f16_t* __restrict__ dst)
{
  int idx = blockIdx.x * 256 + threadIdx.x;        // 32768 float4 tasks
  float4 a = *(const float4*)(Wfc + (size_t)idx * 4);
  f16_t* d = dst + (size_t)idx * 4;
  d[0] = (f16_t)a.x; d[1] = (f16_t)a.y; d[2] = (f16_t)a.z; d[3] = (f16_t)a.w;
}

// ---------------------------------------------------------------------------
// Stage A: projections.  Block = 128 pixels; X staged ONCE (64 KB LDS, f16,
// [p][k=256] with chunk swizzle g ^ (p&7) ^ ((p>>3)&7)); loop 4 otiles inside;
// B-fragments gathered directly from L2-hot W_f16 (no LDS, no barriers).
// grid: [3 proj][4 b][128 ptile] = 1536 blocks x 256 thr
// ---------------------------------------------------------------------------
__global__ __launch_bounds__(256, 2) void proj_kernel(
    const float* __restrict__ xq, const float* __restrict__ xk, const float* __restrict__ xv,
    const f16_t* __restrict__ Wall,
    f16_t* __restrict__ qh, f16_t* __restrict__ kh, f16_t* __restrict__ vh)
{
  int bid = blockIdx.x;
  const int pt = bid & 127; bid >>= 7;
  const int b  = bid & 3;   bid >>= 2;
  const int proj = bid;

  const float* X = (proj == 0) ? xq : (proj == 1) ? xk : xv;
  const f16_t* Wf = Wall + (size_t)proj * 131072;
  f16_t* OUT     = (proj == 0) ? qh : (proj == 1) ? kh : vh;

  const int p0 = pt * 128;
  __shared__ __align__(16) f16_t Xl[128 * 256];  // 64 KB

  const int tid = threadIdx.x;
  const int lane = tid & 63, wv = tid >> 6;
  const int wp = (wv & 1) * 64, wo = (wv >> 1) * 64;
  const int l15 = lane & 15, q4 = lane >> 4;

  const size_t xbase = (size_t)b * 256 * 16384;

  // stage X tile [c=256][p=128] fp32 -> LDS [p][k] f16, c-pairs as h2
#pragma unroll
  for (int t = 0; t < 16; ++t) {
    int task = t * 256 + tid;            // 4096 tasks: (c2 128) x (p4 32)
    int c2 = task >> 5, p4 = task & 31;
    int c0 = c2 * 2;
    float4 a0 = *(const float4*)(X + xbase + (size_t)c0 * 16384 + p0 + p4 * 4);
    float4 a1 = *(const float4*)(X + xbase + (size_t)(c0 + 1) * 16384 + p0 + p4 * 4);
    const float* f0 = &a0.x; const float* f1 = &a1.x;
    int g = c0 >> 3;
#pragma unroll
    for (int i = 0; i < 4; ++i) {
      int p = p4 * 4 + i;
      int sw = (p & 7) ^ ((p >> 3) & 7);
      h2 val = (h2){(f16_t)f0[i], (f16_t)f1[i]};
      *(h2*)&Xl[(p << 8) + ((g ^ sw) << 3) + (c0 & 7)] = val;
    }
  }
  __syncthreads();

#pragma unroll 1
  for (int ot = 0; ot < 4; ++ot) {
    f32x4 acc[4][4];
#pragma unroll
    for (int i = 0; i < 4; ++i)
#pragma unroll
      for (int j = 0; j < 4; ++j) acc[i][j] = (f32x4){0.f, 0.f, 0.f, 0.f};

#pragma unroll
    for (int kc = 0; kc < 4; ++kc) {
#pragma unroll
      for (int ks = 0; ks < 2; ++ks) {
        const int gq = kc * 8 + ks * 4 + q4;     // chunk 0..31
        f16x8 af[4], bfr[4];
#pragma unroll
        for (int i = 0; i < 4; ++i) {
          int p = wp + i * 16 + l15;
          int sw = (p & 7) ^ ((p >> 3) & 7);
          int gs = (gq & 0x18) | ((gq ^ sw) & 7);
          af[i] = *(const f16x8*)&Xl[(p << 8) + (gs << 3)];
        }
#pragma unroll
        for (int j = 0; j < 4; ++j) {
          int o = ot * 128 + wo + j * 16 + l15;
          bfr[j] = *(const f16x8*)(Wf + (size_t)o * 256 + kc * 64 + ks * 32 + q4 * 8);
        }
#pragma unroll
        for (int i = 0; i < 4; ++i)
#pragma unroll
          for (int j = 0; j < 4; ++j)
            acc[i][j] = MFMA_F16(af[i], bfr[j], acc[i][j]);
      }
    }

#pragma unroll
    for (int i = 0; i < 4; ++i) {
#pragma unroll
      for (int j = 0; j < 4; ++j) {
        int o = ot * 128 + wo + j * 16 + l15;
        int nn = o >> 6, d = o & 63;
#pragma unroll
        for (int r = 0; r < 4; ++r) {
          int p = p0 + wp + i * 16 + q4 * 4 + r;
          OUT[(((size_t)b * 8 + nn) * 16384 + p) * 64 + d] = (f16_t)acc[i][j][r];
        }
      }
    }
  }
}

// ---------------------------------------------------------------------------
// Stage B: 7x7 local attention, online softmax, dy-paired.
// v4: 8 rows x 32 w per block, 256 threads = (rp 4, w 32, dg 2).
// Ring = 2 slots x 38 px x 16 chunks x 16 B = 19456 B LDS -> 8 blocks/CU
// (32 waves/CU, 2x v1) while keeping v3's halved row-halo (14 loaded rows
// per 8 computed).  VGPR stays 64 (same per-thread body) so 8 waves/SIMD fit.
// Zero halo == reference zero padding (OOB logits 0 participate in softmax).
// grid: [4 b][8 n][16 rowoct][4 wquarter] = 2048 blocks x 256 thr
// ---------------------------------------------------------------------------
__global__ __launch_bounds__(256, 4) void attn_kernel(
    const f16_t* __restrict__ qh, const f16_t* __restrict__ kh,
    const f16_t* __restrict__ vh, f16_t* __restrict__ ao)
{
  int bid = blockIdx.x;
  const int wq = bid & 3;   bid >>= 2;
  const int oc8 = bid & 15; bid >>= 4;
  const int n  = bid & 7;  bid >>= 3;
  const int b  = bid;
  const int h0 = oc8 * 8, w0 = wq * 32;

  const int tid = threadIdx.x;
  const int rp = tid >> 6;          // row-pair 0..3 (wave-uniform)
  const int w  = (tid >> 1) & 31;
  const int dg = tid & 1;           // 32-channel group
  const int dg4 = dg * 4;
  const int hA = h0 + 2 * rp, hB = hA + 1;

  const size_t headoff = ((size_t)b * 8 + n) * 16384 * 64;
  const f16_t* Qh = qh + headoff;
  const f16_t* Kh = kh + headoff;
  const f16_t* Vh = vh + headoff;

  __shared__ uint4 ring[2][38 * 16];  // [slot][pix*16 + (oc ^ (pix&15))]

  union Pack { uint4 u[4]; h2 h[16]; };

  Pack quA, quB;
  {
    const uint4* qa = (const uint4*)(Qh + ((size_t)hA * 128 + w0 + w) * 64 + dg * 32);
    const uint4* qb = (const uint4*)(Qh + ((size_t)hB * 128 + w0 + w) * 64 + dg * 32);
#pragma unroll
    for (int j = 0; j < 4; ++j) { quA.u[j] = qa[j]; quB.u[j] = qb[j]; }
  }

  auto load_row = [&](int r, int slot) {
    const bool rok = (r >= 0) && (r < 128);
#pragma unroll
    for (int t = 0; t < 3; ++t) {
      int task = t * 256 + tid;            // 38*16 = 608 16B-chunk tasks
      if (task < 608) {
        int pix = task >> 4, oc = task & 15;
        int ww = w0 + pix - 3;
        uint4 val = make_uint4(0u, 0u, 0u, 0u);
        if (rok && ww >= 0 && ww < 128) {
          const f16_t* src = (oc < 8)
              ? (Kh + ((size_t)r * 128 + ww) * 64 + oc * 8)
              : (Vh + ((size_t)r * 128 + ww) * 64 + (oc - 8) * 8);
          val = *(const uint4*)src;
        }
        ring[slot][(pix << 4) + (oc ^ (pix & 15))] = val;
      }
    }
  };

  const float cscale = 0.18033688011112042f;  // (1/8) * log2(e)

  float mA = -3.0e38f, lA = 0.f, mB = -3.0e38f, lB = 0.f;
  h2 ovA[16], ovB[16];
#pragma unroll
  for (int j = 0; j < 16; ++j) { ovA[j] = (h2){(f16_t)0.f, (f16_t)0.f}; ovB[j] = ovA[j]; }

  load_row(h0 - 3, 0);
  __syncthreads();

#pragma unroll 1
  for (int it = 0; it < 14; ++it) {
    if (it < 13) load_row(h0 - 2 + it, (it + 1) & 1);  // prefetch next row
    const uint4* cur = ring[it & 1];
    const int dyA = it - 2 * rp;                        // wave-uniform
    const int dyB = dyA - 1;
    const bool aA = (dyA >= 0) && (dyA < 7);
    const bool aB = (dyB >= 0) && (dyB < 7);
    if (aA || aB) {
      // ---- scores vs this k-row for both owned pixels ----
      float sA[7], sB[7];
#pragma unroll
      for (int dx = 0; dx < 7; ++dx) {
        const int pix = w + dx, sw = pix & 15, base = pix << 4;
        Pack ku;
        ku.u[0] = cur[base + ((dg4 + 0) ^ sw)];
        ku.u[1] = cur[base + ((dg4 + 1) ^ sw)];
        ku.u[2] = cur[base + ((dg4 + 2) ^ sw)];
        ku.u[3] = cur[base + ((dg4 + 3) ^ sw)];
        float accA = 0.f, accB = 0.f;
#pragma unroll
        for (int j = 0; j < 16; ++j) {
          accA = fdot2_(quA.h[j], ku.h[j], accA);
          accB = fdot2_(quB.h[j], ku.h[j], accB);
        }
        sA[dx] = accA; sB[dx] = accB;
      }
#pragma unroll
      for (int dx = 0; dx < 7; ++dx) {
        sA[dx] = (sA[dx] + __shfl_xor(sA[dx], 1)) * cscale;
        sB[dx] = (sB[dx] + __shfl_xor(sB[dx], 1)) * cscale;
      }

      // ---- online softmax updates ----
      h2 eA[7], eB[7];
      if (aA) {
        float nm = mA;
#pragma unroll
        for (int dx = 0; dx < 7; ++dx) nm = fmaxf(nm, sA[dx]);
        float alpha = exp2f(mA - nm);
        mA = nm; lA *= alpha;
        f16_t ah = (f16_t)alpha; h2 a2 = (h2){ah, ah};
#pragma unroll
        for (int j = 0; j < 16; ++j) ovA[j] *= a2;
#pragma unroll
        for (int dx = 0; dx < 7; ++dx) {
          float e = exp2f(sA[dx] - mA);
          lA += e; f16_t eh = (f16_t)e; eA[dx] = (h2){eh, eh};
        }
      }
      if (aB) {
        float nm = mB;
#pragma unroll
        for (int dx = 0; dx < 7; ++dx) nm = fmaxf(nm, sB[dx]);
        float alpha = exp2f(mB - nm);
        mB = nm; lB *= alpha;
        f16_t ah = (f16_t)alpha; h2 a2 = (h2){ah, ah};
#pragma unroll
        for (int j = 0; j < 16; ++j) ovB[j] *= a2;
#pragma unroll
        for (int dx = 0; dx < 7; ++dx) {
          float e = exp2f(sB[dx] - mB);
          lB += e; f16_t eh = (f16_t)e; eB[dx] = (h2){eh, eh};
        }
      }

      // ---- weighted V (chunk read shared by both pixels) ----
#pragma unroll
      for (int dx = 0; dx < 7; ++dx) {
        const int pix = w + dx, sw = pix & 15, base = pix << 4;
        Pack vu;
        vu.u[0] = cur[base + ((8 + dg4 + 0) ^ sw)];
        vu.u[1] = cur[base + ((8 + dg4 + 1) ^ sw)];
        vu.u[2] = cur[base + ((8 + dg4 + 2) ^ sw)];
        vu.u[3] = cur[base + ((8 + dg4 + 3) ^ sw)];
        if (aA) {
#pragma unroll
          for (int j = 0; j < 16; ++j) ovA[j] = eA[dx] * vu.h[j] + ovA[j];
        }
        if (aB) {
#pragma unroll
          for (int j = 0; j < 16; ++j) ovB[j] = eB[dx] * vu.h[j] + ovB[j];
        }
      }
    }
    __syncthreads();
  }

  // epilogue: normalize, store 32 f16 channels per owned pixel
  {
    float inv = 1.0f / lA; f16_t ih = (f16_t)inv; h2 i2 = (h2){ih, ih};
    Pack ou;
#pragma unroll
    for (int j = 0; j < 16; ++j) ou.h[j] = ovA[j] * i2;
    uint4* d4 = (uint4*)(ao + (((size_t)b * 16384) + (size_t)hA * 128 + (w0 + w)) * 512 + n * 64 + dg * 32);
    d4[0] = ou.u[0]; d4[1] = ou.u[1]; d4[2] = ou.u[2]; d4[3] = ou.u[3];
  }
  {
    float inv = 1.0f / lB; f16_t ih = (f16_t)inv; h2 i2 = (h2){ih, ih};
    Pack ou;
#pragma unroll
    for (int j = 0; j < 16; ++j) ou.h[j] = ovB[j] * i2;
    uint4* d4 = (uint4*)(ao + (((size_t)b * 16384) + (size_t)hB * 128 + (w0 + w)) * 512 + n * 64 + dg * 32);
    d4[0] = ou.u[0]; d4[1] = ou.u[1]; d4[2] = ou.u[2]; d4[3] = ou.u[3];
  }
}

// ---------------------------------------------------------------------------
// Stage C: o = Wfc @ ao + residual, LayerNorm over C=256, fused.
// ao tile staged ONCE ([p=64][k=512] f16, 64 KB); A-fragments of Wfc_f16
// gathered directly from L2-hot global.  2 barriers/block.
// grid: [4 b][256 ptile(64)] = 1024 blocks x 256 thr
// ---------------------------------------------------------------------------
__global__ __launch_bounds__(256, 2) void fc_ln_kernel(
    const f16_t* __restrict__ ao, const f16_t* __restrict__ Wfc16,
    const float* __restrict__ resid, const float* __restrict__ lnw,
    const float* __restrict__ lnb, float* __restrict__ outp)
{
  int bid = blockIdx.x;
  const int pt = bid & 255;
  const int b = bid >> 8;
  const int p0 = pt * 64;

  const int tid = threadIdx.x;
  const int lane = tid & 63, wv = tid >> 6;
  const int c0w = wv * 64;
  const int l15 = lane & 15, q4 = lane >> 4;

  __shared__ __align__(16) f16_t Bl[64 * 512];  // ao tile [p][k], 64 KB
  __shared__ float lnws[256], lnbs[256];
  __shared__ float red[2][4][64];

  lnws[tid] = lnw[tid];
  lnbs[tid] = lnb[tid];

  // stage full ao tile once
#pragma unroll
  for (int t = 0; t < 16; ++t) {
    int task = t * 256 + tid;            // 4096 tasks: (p 64) x (g 64)
    int p = task >> 6, g = task & 63;
    uint4 v4 = *(const uint4*)(ao + ((size_t)b * 16384 + p0 + p) * 512 + g * 8);
    int gs = (g & 0x38) | ((g ^ (p & 7)) & 7);
    *(uint4*)&Bl[(p << 9) + (gs << 3)] = v4;
  }
  __syncthreads();

  f32x4 acc[4][4];
#pragma unroll
  for (int i = 0; i < 4; ++i)
#pragma unroll
    for (int j = 0; j < 4; ++j) acc[i][j] = (f32x4){0.f, 0.f, 0.f, 0.f};

#pragma unroll 1
  for (int kc = 0; kc < 8; ++kc) {
#pragma unroll
    for (int ks = 0; ks < 2; ++ks) {
      const int gq = kc * 8 + ks * 4 + q4;     // chunk 0..63
      f16x8 af[4], bfr[4];
#pragma unroll
      for (int i = 0; i < 4; ++i) {
        int c = c0w + i * 16 + l15;
        af[i] = *(const f16x8*)(Wfc16 + (size_t)c * 512 + kc * 64 + ks * 32 + q4 * 8);
      }
#pragma unroll
      for (int j = 0; j < 4; ++j) {
        int p = j * 16 + l15;
        int gs = (gq & 0x38) | ((gq ^ (p & 7)) & 7);
        bfr[j] = *(const f16x8*)&Bl[(p << 9) + (gs << 3)];
      }
#pragma unroll
      for (int i = 0; i < 4; ++i)
#pragma unroll
        for (int j = 0; j < 4; ++j)
          acc[i][j] = MFMA_F16(af[i], bfr[j], acc[i][j]);
    }
  }

  float s[4], s2[4];
#pragma unroll
  for (int j = 0; j < 4; ++j) { s[j] = 0.f; s2[j] = 0.f; }
#pragma unroll
  for (int i = 0; i < 4; ++i) {
#pragma unroll
    for (int r = 0; r < 4; ++r) {
      int c = c0w + i * 16 + q4 * 4 + r;
      const float* rp = resid + ((size_t)b * 256 + c) * 16384 + p0;
#pragma unroll
      for (int j = 0; j < 4; ++j) {
        float v = acc[i][j][r] + rp[j * 16 + l15];
        acc[i][j][r] = v;
        s[j] += v; s2[j] += v * v;
      }
    }
  }
#pragma unroll
  for (int j = 0; j < 4; ++j) {
    s[j]  += __shfl_xor(s[j], 16);
    s[j]  += __shfl_xor(s[j], 32);
    s2[j] += __shfl_xor(s2[j], 16);
    s2[j] += __shfl_xor(s2[j], 32);
  }
  if (q4 == 0) {
#pragma unroll
    for (int j = 0; j < 4; ++j) {
      red[0][wv][j * 16 + l15] = s[j];
      red[1][wv][j * 16 + l15] = s2[j];
    }
  }
  __syncthreads();
#pragma unroll
  for (int j = 0; j < 4; ++j) {
    int pl = j * 16 + l15;
    float ts  = red[0][0][pl] + red[0][1][pl] + red[0][2][pl] + red[0][3][pl];
    float ts2 = red[1][0][pl] + red[1][1][pl] + red[1][2][pl] + red[1][3][pl];
    float mean = ts * (1.f / 256.f);
    float var  = ts2 * (1.f / 256.f) - mean * mean;
    float rstd = rsqrtf(var + 1e-6f);
#pragma unroll
    for (int i = 0; i < 4; ++i) {
#pragma unroll
      for (int r = 0; r < 4; ++r) {
        int c = c0w + i * 16 + q4 * 4 + r;
        outp[((size_t)b * 256 + c) * 16384 + p0 + pl] =
            (acc[i][j][r] - mean) * rstd * lnws[c] + lnbs[c];
      }
    }
  }
}

// ---------------------------------------------------------------------------
extern "C" void kernel_launch(void* const* d_in, const int* in_sizes, int n_in,
                              void* d_out, int out_size, void* d_ws, size_t ws_size,
                              hipStream_t stream) {
  const float* q   = (const float*)d_in[0];
  const float* k   = (const float*)d_in[1];
  const float* v   = (const float*)d_in[2];
  const float* Wq  = (const float*)d_in[3];
  const float* Wk  = (const float*)d_in[4];
  const float* Wv  = (const float*)d_in[5];
  const float* Wfc = (const float*)d_in[6];
  const float* lnw = (const float*)d_in[7];
  const float* lnb = (const float*)d_in[8];
  float* outp = (float*)d_out;

  // workspace: 4 x 64 MiB f16 regions; W_f16 copies overlay dead regions:
  //   Wqkv_f16 -> head of ao region (dead until attn rewrites it fully)
  //   Wfc_f16  -> head of qh region (dead after attn)
  f16_t* qh = (f16_t*)d_ws;
  f16_t* kh = qh + 33554432ULL;
  f16_t* vh = kh + 33554432ULL;
  f16_t* ao = vh + 33554432ULL;
  f16_t* Wqkv16 = ao;   // 393216 f16, consumed by proj before attn writes ao
  f16_t* Wfc16  = qh;   // 131072 f16, written after attn, consumed by fc_ln

  wconvA_kernel<<<dim3(384), dim3(256), 0, stream>>>(Wq, Wk, Wv, Wqkv16);
  proj_kernel<<<dim3(1536), dim3(256), 0, stream>>>(q, k, v, Wqkv16, qh, kh, vh);
  attn_kernel<<<dim3(2048), dim3(256), 0, stream>>>(qh, kh, vh, ao);
  wconvB_kernel<<<dim3(128), dim3(256), 0, stream>>>(Wfc, Wfc16);
  fc_ln_kernel<<<dim3(1024), dim3(256), 0, stream>>>(ao, Wfc16, q, lnw, lnb, outp);
}

// Round 5
// 595.069 us; speedup vs baseline: 1.4294x; 1.4294x over previous
//
#include <hip/hip_runtime.h>
#include <hip/hip_bf16.h>
#include <cstdint>
#include <cstddef>

typedef _Float16 f16_t;
typedef _Float16 h2    __attribute__((ext_vector_type(2)));
typedef _Float16 f16x8 __attribute__((ext_vector_type(8)));
typedef float    f32x4 __attribute__((ext_vector_type(4)));

#define MFMA_F16(A, Bv, Cv) __builtin_amdgcn_mfma_f32_16x16x32_f16((A), (Bv), (Cv), 0, 0, 0)

__device__ __forceinline__ float fdot2_(h2 a, h2 b, float c) {
#if __has_builtin(__builtin_amdgcn_fdot2)
  return __builtin_amdgcn_fdot2(a, b, c, false);
#else
  return c + (float)a[0] * (float)b[0] + (float)a[1] * (float)b[1];
#endif
}

// ---------------------------------------------------------------------------
// W fp32 -> f16 converters (run while target ws region is dead).
// ---------------------------------------------------------------------------
__global__ __launch_bounds__(256) void wconvA_kernel(
    const float* __restrict__ Wq, const float* __restrict__ Wk,
    const float* __restrict__ Wv, f16_t* __restrict__ dst)
{
  int idx = blockIdx.x * 256 + threadIdx.x;        // 98304 float4 tasks
  int src = idx >> 15, off = idx & 32767;
  const float* W = (src == 0) ? Wq : (src == 1) ? Wk : Wv;
  float4 a = *(const float4*)(W + (size_t)off * 4);
  f16_t* d = dst + (size_t)src * 131072 + (size_t)off * 4;
  d[0] = (f16_t)a.x; d[1] = (f16_t)a.y; d[2] = (f16_t)a.z; d[3] = (f16_t)a.w;
}

__global__ __launch_bounds__(256) void wconvB_kernel(
    const float* __restrict__ Wfc, f16_t* __restrict__ dst)
{
  int idx = blockIdx.x * 256 + threadIdx.x;        // 32768 float4 tasks
  float4 a = *(const float4*)(Wfc + (size_t)idx * 4);
  f16_t* d = dst + (size_t)idx * 4;
  d[0] = (f16_t)a.x; d[1] = (f16_t)a.y; d[2] = (f16_t)a.z; d[3] = (f16_t)a.w;
}

// ---------------------------------------------------------------------------
// Stage A: projections.  Block = 128 pixels; X staged ONCE (64 KB LDS, f16,
// [p][k=256] with chunk swizzle g ^ (p&7) ^ ((p>>3)&7)); loop 4 otiles inside;
// B-fragments gathered directly from L2-hot W_f16 (no LDS, no barriers).
// grid: [3 proj][4 b][128 ptile] = 1536 blocks x 256 thr
// ---------------------------------------------------------------------------
__global__ __launch_bounds__(256, 2) void proj_kernel(
    const float* __restrict__ xq, const float* __restrict__ xk, const float* __restrict__ xv,
    const f16_t* __restrict__ Wall,
    f16_t* __restrict__ qh, f16_t* __restrict__ kh, f16_t* __restrict__ vh)
{
  int bid = blockIdx.x;
  const int pt = bid & 127; bid >>= 7;
  const int b  = bid & 3;   bid >>= 2;
  const int proj = bid;

  const float* X = (proj == 0) ? xq : (proj == 1) ? xk : xv;
  const f16_t* Wf = Wall + (size_t)proj * 131072;
  f16_t* OUT     = (proj == 0) ? qh : (proj == 1) ? kh : vh;

  const int p0 = pt * 128;
  __shared__ __align__(16) f16_t Xl[128 * 256];  // 64 KB

  const int tid = threadIdx.x;
  const int lane = tid & 63, wv = tid >> 6;
  const int wp = (wv & 1) * 64, wo = (wv >> 1) * 64;
  const int l15 = lane & 15, q4 = lane >> 4;

  const size_t xbase = (size_t)b * 256 * 16384;

  // stage X tile [c=256][p=128] fp32 -> LDS [p][k] f16, c-pairs as h2
#pragma unroll
  for (int t = 0; t < 16; ++t) {
    int task = t * 256 + tid;            // 4096 tasks: (c2 128) x (p4 32)
    int c2 = task >> 5, p4 = task & 31;
    int c0 = c2 * 2;
    float4 a0 = *(const float4*)(X + xbase + (size_t)c0 * 16384 + p0 + p4 * 4);
    float4 a1 = *(const float4*)(X + xbase + (size_t)(c0 + 1) * 16384 + p0 + p4 * 4);
    const float* f0 = &a0.x; const float* f1 = &a1.x;
    int g = c0 >> 3;
#pragma unroll
    for (int i = 0; i < 4; ++i) {
      int p = p4 * 4 + i;
      int sw = (p & 7) ^ ((p >> 3) & 7);
      h2 val = (h2){(f16_t)f0[i], (f16_t)f1[i]};
      *(h2*)&Xl[(p << 8) + ((g ^ sw) << 3) + (c0 & 7)] = val;
    }
  }
  __syncthreads();

#pragma unroll 1
  for (int ot = 0; ot < 4; ++ot) {
    f32x4 acc[4][4];
#pragma unroll
    for (int i = 0; i < 4; ++i)
#pragma unroll
      for (int j = 0; j < 4; ++j) acc[i][j] = (f32x4){0.f, 0.f, 0.f, 0.f};

#pragma unroll
    for (int kc = 0; kc < 4; ++kc) {
#pragma unroll
      for (int ks = 0; ks < 2; ++ks) {
        const int gq = kc * 8 + ks * 4 + q4;     // chunk 0..31
        f16x8 af[4], bfr[4];
#pragma unroll
        for (int i = 0; i < 4; ++i) {
          int p = wp + i * 16 + l15;
          int sw = (p & 7) ^ ((p >> 3) & 7);
          int gs = (gq & 0x18) | ((gq ^ sw) & 7);
          af[i] = *(const f16x8*)&Xl[(p << 8) + (gs << 3)];
        }
#pragma unroll
        for (int j = 0; j < 4; ++j) {
          int o = ot * 128 + wo + j * 16 + l15;
          bfr[j] = *(const f16x8*)(Wf + (size_t)o * 256 + kc * 64 + ks * 32 + q4 * 8);
        }
#pragma unroll
        for (int i = 0; i < 4; ++i)
#pragma unroll
          for (int j = 0; j < 4; ++j)
            acc[i][j] = MFMA_F16(af[i], bfr[j], acc[i][j]);
      }
    }

#pragma unroll
    for (int i = 0; i < 4; ++i) {
#pragma unroll
      for (int j = 0; j < 4; ++j) {
        int o = ot * 128 + wo + j * 16 + l15;
        int nn = o >> 6, d = o & 63;
#pragma unroll
        for (int r = 0; r < 4; ++r) {
          int p = p0 + wp + i * 16 + q4 * 4 + r;
          OUT[(((size_t)b * 8 + nn) * 16384 + p) * 64 + d] = (f16_t)acc[i][j][r];
        }
      }
    }
  }
}

// ---------------------------------------------------------------------------
// Stage B: 7x7 local attention, online softmax, dy-paired.
// v5: SAME geometry as v4 (8 rows x 32 w, 256 thr, 19456 B ring, 14 its).
// ONE change: __launch_bounds__(256, 2).  Diagnosis: live per-thread state is
// ~90 VGPRs (qu 16 + ov 32 + s 14 + e 7 + m/l 4 + addr), but the allocator
// clamped to 64 (8-wave heuristic) and SPILLED the rest -> ~500 MB scratch
// fetch + ~290 MB scratch write per dispatch (measured 846/356 MB vs ~346/67
// ideal).  dur tracked hbm_bytes/2.5TB/s exactly across v1/v3/v4 -> kernel is
// traffic-bound and the traffic is spills.  (256,2) lifts the VGPR cap to 256
// so the working set stays in registers.
// grid: [4 b][8 n][16 rowoct][4 wquarter] = 2048 blocks x 256 thr
// ---------------------------------------------------------------------------
__global__ __launch_bounds__(256, 2) void attn_kernel(
    const f16_t* __restrict__ qh, const f16_t* __restrict__ kh,
    const f16_t* __restrict__ vh, f16_t* __restrict__ ao)
{
  int bid = blockIdx.x;
  const int wq = bid & 3;   bid >>= 2;
  const int oc8 = bid & 15; bid >>= 4;
  const int n  = bid & 7;  bid >>= 3;
  const int b  = bid;
  const int h0 = oc8 * 8, w0 = wq * 32;

  const int tid = threadIdx.x;
  const int rp = tid >> 6;          // row-pair 0..3 (wave-uniform)
  const int w  = (tid >> 1) & 31;
  const int dg = tid & 1;           // 32-channel group
  const int dg4 = dg * 4;
  const int hA = h0 + 2 * rp, hB = hA + 1;

  const size_t headoff = ((size_t)b * 8 + n) * 16384 * 64;
  const f16_t* Qh = qh + headoff;
  const f16_t* Kh = kh + headoff;
  const f16_t* Vh = vh + headoff;

  __shared__ uint4 ring[2][38 * 16];  // [slot][pix*16 + (oc ^ (pix&15))]

  union Pack { uint4 u[4]; h2 h[16]; };

  Pack quA, quB;
  {
    const uint4* qa = (const uint4*)(Qh + ((size_t)hA * 128 + w0 + w) * 64 + dg * 32);
    const uint4* qb = (const uint4*)(Qh + ((size_t)hB * 128 + w0 + w) * 64 + dg * 32);
#pragma unroll
    for (int j = 0; j < 4; ++j) { quA.u[j] = qa[j]; quB.u[j] = qb[j]; }
  }

  auto load_row = [&](int r, int slot) {
    const bool rok = (r >= 0) && (r < 128);
#pragma unroll
    for (int t = 0; t < 3; ++t) {
      int task = t * 256 + tid;            // 38*16 = 608 16B-chunk tasks
      if (task < 608) {
        int pix = task >> 4, oc = task & 15;
        int ww = w0 + pix - 3;
        uint4 val = make_uint4(0u, 0u, 0u, 0u);
        if (rok && ww >= 0 && ww < 128) {
          const f16_t* src = (oc < 8)
              ? (Kh + ((size_t)r * 128 + ww) * 64 + oc * 8)
              : (Vh + ((size_t)r * 128 + ww) * 64 + (oc - 8) * 8);
          val = *(const uint4*)src;
        }
        ring[slot][(pix << 4) + (oc ^ (pix & 15))] = val;
      }
    }
  };

  const float cscale = 0.18033688011112042f;  // (1/8) * log2(e)

  float mA = -3.0e38f, lA = 0.f, mB = -3.0e38f, lB = 0.f;
  h2 ovA[16], ovB[16];
#pragma unroll
  for (int j = 0; j < 16; ++j) { ovA[j] = (h2){(f16_t)0.f, (f16_t)0.f}; ovB[j] = ovA[j]; }

  load_row(h0 - 3, 0);
  __syncthreads();

#pragma unroll 1
  for (int it = 0; it < 14; ++it) {
    if (it < 13) load_row(h0 - 2 + it, (it + 1) & 1);  // prefetch next row
    const uint4* cur = ring[it & 1];
    const int dyA = it - 2 * rp;                        // wave-uniform
    const int dyB = dyA - 1;
    const bool aA = (dyA >= 0) && (dyA < 7);
    const bool aB = (dyB >= 0) && (dyB < 7);
    if (aA || aB) {
      // ---- scores vs this k-row for both owned pixels ----
      float sA[7], sB[7];
#pragma unroll
      for (int dx = 0; dx < 7; ++dx) {
        const int pix = w + dx, sw = pix & 15, base = pix << 4;
        Pack ku;
        ku.u[0] = cur[base + ((dg4 + 0) ^ sw)];
        ku.u[1] = cur[base + ((dg4 + 1) ^ sw)];
        ku.u[2] = cur[base + ((dg4 + 2) ^ sw)];
        ku.u[3] = cur[base + ((dg4 + 3) ^ sw)];
        float accA = 0.f, accB = 0.f;
#pragma unroll
        for (int j = 0; j < 16; ++j) {
          accA = fdot2_(quA.h[j], ku.h[j], accA);
          accB = fdot2_(quB.h[j], ku.h[j], accB);
        }
        sA[dx] = accA; sB[dx] = accB;
      }
#pragma unroll
      for (int dx = 0; dx < 7; ++dx) {
        sA[dx] = (sA[dx] + __shfl_xor(sA[dx], 1)) * cscale;
        sB[dx] = (sB[dx] + __shfl_xor(sB[dx], 1)) * cscale;
      }

      // ---- online softmax updates ----
      h2 eA[7], eB[7];
      if (aA) {
        float nm = mA;
#pragma unroll
        for (int dx = 0; dx < 7; ++dx) nm = fmaxf(nm, sA[dx]);
        float alpha = exp2f(mA - nm);
        mA = nm; lA *= alpha;
        f16_t ah = (f16_t)alpha; h2 a2 = (h2){ah, ah};
#pragma unroll
        for (int j = 0; j < 16; ++j) ovA[j] *= a2;
#pragma unroll
        for (int dx = 0; dx < 7; ++dx) {
          float e = exp2f(sA[dx] - mA);
          lA += e; f16_t eh = (f16_t)e; eA[dx] = (h2){eh, eh};
        }
      }
      if (aB) {
        float nm = mB;
#pragma unroll
        for (int dx = 0; dx < 7; ++dx) nm = fmaxf(nm, sB[dx]);
        float alpha = exp2f(mB - nm);
        mB = nm; lB *= alpha;
        f16_t ah = (f16_t)alpha; h2 a2 = (h2){ah, ah};
#pragma unroll
        for (int j = 0; j < 16; ++j) ovB[j] *= a2;
#pragma unroll
        for (int dx = 0; dx < 7; ++dx) {
          float e = exp2f(sB[dx] - mB);
          lB += e; f16_t eh = (f16_t)e; eB[dx] = (h2){eh, eh};
        }
      }

      // ---- weighted V (chunk read shared by both pixels) ----
#pragma unroll
      for (int dx = 0; dx < 7; ++dx) {
        const int pix = w + dx, sw = pix & 15, base = pix << 4;
        Pack vu;
        vu.u[0] = cur[base + ((8 + dg4 + 0) ^ sw)];
        vu.u[1] = cur[base + ((8 + dg4 + 1) ^ sw)];
        vu.u[2] = cur[base + ((8 + dg4 + 2) ^ sw)];
        vu.u[3] = cur[base + ((8 + dg4 + 3) ^ sw)];
        if (aA) {
#pragma unroll
          for (int j = 0; j < 16; ++j) ovA[j] = eA[dx] * vu.h[j] + ovA[j];
        }
        if (aB) {
#pragma unroll
          for (int j = 0; j < 16; ++j) ovB[j] = eB[dx] * vu.h[j] + ovB[j];
        }
      }
    }
    __syncthreads();
  }

  // epilogue: normalize, store 32 f16 channels per owned pixel
  {
    float inv = 1.0f / lA; f16_t ih = (f16_t)inv; h2 i2 = (h2){ih, ih};
    Pack ou;
#pragma unroll
    for (int j = 0; j < 16; ++j) ou.h[j] = ovA[j] * i2;
    uint4* d4 = (uint4*)(ao + (((size_t)b * 16384) + (size_t)hA * 128 + (w0 + w)) * 512 + n * 64 + dg * 32);
    d4[0] = ou.u[0]; d4[1] = ou.u[1]; d4[2] = ou.u[2]; d4[3] = ou.u[3];
  }
  {
    float inv = 1.0f / lB; f16_t ih = (f16_t)inv; h2 i2 = (h2){ih, ih};
    Pack ou;
#pragma unroll
    for (int j = 0; j < 16; ++j) ou.h[j] = ovB[j] * i2;
    uint4* d4 = (uint4*)(ao + (((size_t)b * 16384) + (size_t)hB * 128 + (w0 + w)) * 512 + n * 64 + dg * 32);
    d4[0] = ou.u[0]; d4[1] = ou.u[1]; d4[2] = ou.u[2]; d4[3] = ou.u[3];
  }
}

// ---------------------------------------------------------------------------
// Stage C: o = Wfc @ ao + residual, LayerNorm over C=256, fused.
// ao tile staged ONCE ([p=64][k=512] f16, 64 KB); A-fragments of Wfc_f16
// gathered directly from L2-hot global.  2 barriers/block.
// grid: [4 b][256 ptile(64)] = 1024 blocks x 256 thr
// ---------------------------------------------------------------------------
__global__ __launch_bounds__(256, 2) void fc_ln_kernel(
    const f16_t* __restrict__ ao, const f16_t* __restrict__ Wfc16,
    const float* __restrict__ resid, const float* __restrict__ lnw,
    const float* __restrict__ lnb, float* __restrict__ outp)
{
  int bid = blockIdx.x;
  const int pt = bid & 255;
  const int b = bid >> 8;
  const int p0 = pt * 64;

  const int tid = threadIdx.x;
  const int lane = tid & 63, wv = tid >> 6;
  const int c0w = wv * 64;
  const int l15 = lane & 15, q4 = lane >> 4;

  __shared__ __align__(16) f16_t Bl[64 * 512];  // ao tile [p][k], 64 KB
  __shared__ float lnws[256], lnbs[256];
  __shared__ float red[2][4][64];

  lnws[tid] = lnw[tid];
  lnbs[tid] = lnb[tid];

  // stage full ao tile once
#pragma unroll
  for (int t = 0; t < 16; ++t) {
    int task = t * 256 + tid;            // 4096 tasks: (p 64) x (g 64)
    int p = task >> 6, g = task & 63;
    uint4 v4 = *(const uint4*)(ao + ((size_t)b * 16384 + p0 + p) * 512 + g * 8);
    int gs = (g & 0x38) | ((g ^ (p & 7)) & 7);
    *(uint4*)&Bl[(p << 9) + (gs << 3)] = v4;
  }
  __syncthreads();

  f32x4 acc[4][4];
#pragma unroll
  for (int i = 0; i < 4; ++i)
#pragma unroll
    for (int j = 0; j < 4; ++j) acc[i][j] = (f32x4){0.f, 0.f, 0.f, 0.f};

#pragma unroll 1
  for (int kc = 0; kc < 8; ++kc) {
#pragma unroll
    for (int ks = 0; ks < 2; ++ks) {
      const int gq = kc * 8 + ks * 4 + q4;     // chunk 0..63
      f16x8 af[4], bfr[4];
#pragma unroll
      for (int i = 0; i < 4; ++i) {
        int c = c0w + i * 16 + l15;
        af[i] = *(const f16x8*)(Wfc16 + (size_t)c * 512 + kc * 64 + ks * 32 + q4 * 8);
      }
#pragma unroll
      for (int j = 0; j < 4; ++j) {
        int p = j * 16 + l15;
        int gs = (gq & 0x38) | ((gq ^ (p & 7)) & 7);
        bfr[j] = *(const f16x8*)&Bl[(p << 9) + (gs << 3)];
      }
#pragma unroll
      for (int i = 0; i < 4; ++i)
#pragma unroll
        for (int j = 0; j < 4; ++j)
          acc[i][j] = MFMA_F16(af[i], bfr[j], acc[i][j]);
    }
  }

  float s[4], s2[4];
#pragma unroll
  for (int j = 0; j < 4; ++j) { s[j] = 0.f; s2[j] = 0.f; }
#pragma unroll
  for (int i = 0; i < 4; ++i) {
#pragma unroll
    for (int r = 0; r < 4; ++r) {
      int c = c0w + i * 16 + q4 * 4 + r;
      const float* rp = resid + ((size_t)b * 256 + c) * 16384 + p0;
#pragma unroll
      for (int j = 0; j < 4; ++j) {
        float v = acc[i][j][r] + rp[j * 16 + l15];
        acc[i][j][r] = v;
        s[j] += v; s2[j] += v * v;
      }
    }
  }
#pragma unroll
  for (int j = 0; j < 4; ++j) {
    s[j]  += __shfl_xor(s[j], 16);
    s[j]  += __shfl_xor(s[j], 32);
    s2[j] += __shfl_xor(s2[j], 16);
    s2[j] += __shfl_xor(s2[j], 32);
  }
  if (q4 == 0) {
#pragma unroll
    for (int j = 0; j < 4; ++j) {
      red[0][wv][j * 16 + l15] = s[j];
      red[1][wv][j * 16 + l15] = s2[j];
    }
  }
  __syncthreads();
#pragma unroll
  for (int j = 0; j < 4; ++j) {
    int pl = j * 16 + l15;
    float ts  = red[0][0][pl] + red[0][1][pl] + red[0][2][pl] + red[0][3][pl];
    float ts2 = red[1][0][pl] + red[1][1][pl] + red[1][2][pl] + red[1][3][pl];
    float mean = ts * (1.f / 256.f);
    float var  = ts2 * (1.f / 256.f) - mean * mean;
    float rstd = rsqrtf(var + 1e-6f);
#pragma unroll
    for (int i = 0; i < 4; ++i) {
#pragma unroll
      for (int r = 0; r < 4; ++r) {
        int c = c0w + i * 16 + q4 * 4 + r;
        outp[((size_t)b * 256 + c) * 16384 + p0 + pl] =
            (acc[i][j][r] - mean) * rstd * lnws[c] + lnbs[c];
      }
    }
  }
}

// ---------------------------------------------------------------------------
extern "C" void kernel_launch(void* const* d_in, const int* in_sizes, int n_in,
                              void* d_out, int out_size, void* d_ws, size_t ws_size,
                              hipStream_t stream) {
  const float* q   = (const float*)d_in[0];
  const float* k   = (const float*)d_in[1];
  const float* v   = (const float*)d_in[2];
  const float* Wq  = (const float*)d_in[3];
  const float* Wk  = (const float*)d_in[4];
  const float* Wv  = (const float*)d_in[5];
  const float* Wfc = (const float*)d_in[6];
  const float* lnw = (const float*)d_in[7];
  const float* lnb = (const float*)d_in[8];
  float* outp = (float*)d_out;

  // workspace: 4 x 64 MiB f16 regions; W_f16 copies overlay dead regions:
  //   Wqkv_f16 -> head of ao region (dead until attn rewrites it fully)
  //   Wfc_f16  -> head of qh region (dead after attn)
  f16_t* qh = (f16_t*)d_ws;
  f16_t* kh = qh + 33554432ULL;
  f16_t* vh = kh + 33554432ULL;
  f16_t* ao = vh + 33554432ULL;
  f16_t* Wqkv16 = ao;   // 393216 f16, consumed by proj before attn writes ao
  f16_t* Wfc16  = qh;   // 131072 f16, written after attn, consumed by fc_ln

  wconvA_kernel<<<dim3(384), dim3(256), 0, stream>>>(Wq, Wk, Wv, Wqkv16);
  proj_kernel<<<dim3(1536), dim3(256), 0, stream>>>(q, k, v, Wqkv16, qh, kh, vh);
  attn_kernel<<<dim3(2048), dim3(256), 0, stream>>>(qh, kh, vh, ao);
  wconvB_kernel<<<dim3(128), dim3(256), 0, stream>>>(Wfc, Wfc16);
  fc_ln_kernel<<<dim3(1024), dim3(256), 0, stream>>>(ao, Wfc16, q, lnw, lnb, outp);
}

// Round 6
// 554.971 us; speedup vs baseline: 1.5327x; 1.0723x over previous
//
#include <hip/hip_runtime.h>
#include <hip/hip_bf16.h>
#include <cstdint>
#include <cstddef>

typedef _Float16 f16_t;
typedef _Float16 h2    __attribute__((ext_vector_type(2)));
typedef _Float16 f16x8 __attribute__((ext_vector_type(8)));
typedef float    f32x4 __attribute__((ext_vector_type(4)));

#define MFMA_F16(A, Bv, Cv) __builtin_amdgcn_mfma_f32_16x16x32_f16((A), (Bv), (Cv), 0, 0, 0)

__device__ __forceinline__ float fdot2_(h2 a, h2 b, float c) {
#if __has_builtin(__builtin_amdgcn_fdot2)
  return __builtin_amdgcn_fdot2(a, b, c, false);
#else
  return c + (float)a[0] * (float)b[0] + (float)a[1] * (float)b[1];
#endif
}

// ---------------------------------------------------------------------------
// W fp32 -> f16 converters (run while target ws region is dead).
// ---------------------------------------------------------------------------
__global__ __launch_bounds__(256) void wconvA_kernel(
    const float* __restrict__ Wq, const float* __restrict__ Wk,
    const float* __restrict__ Wv, f16_t* __restrict__ dst)
{
  int idx = blockIdx.x * 256 + threadIdx.x;        // 98304 float4 tasks
  int src = idx >> 15, off = idx & 32767;
  const float* W = (src == 0) ? Wq : (src == 1) ? Wk : Wv;
  float4 a = *(const float4*)(W + (size_t)off * 4);
  f16_t* d = dst + (size_t)src * 131072 + (size_t)off * 4;
  d[0] = (f16_t)a.x; d[1] = (f16_t)a.y; d[2] = (f16_t)a.z; d[3] = (f16_t)a.w;
}

__global__ __launch_bounds__(256) void wconvB_kernel(
    const float* __restrict__ Wfc, f16_t* __restrict__ dst)
{
  int idx = blockIdx.x * 256 + threadIdx.x;        // 32768 float4 tasks
  float4 a = *(const float4*)(Wfc + (size_t)idx * 4);
  f16_t* d = dst + (size_t)idx * 4;
  d[0] = (f16_t)a.x; d[1] = (f16_t)a.y; d[2] = (f16_t)a.z; d[3] = (f16_t)a.w;
}

// ---------------------------------------------------------------------------
// Stage A: projections.  Block = 128 pixels; X staged ONCE (64 KB LDS, f16,
// [p][k=256] with chunk swizzle g ^ (p&7) ^ ((p>>3)&7)); loop 4 otiles inside;
// B-fragments gathered directly from L2-hot W_f16 (no LDS, no barriers).
// grid: [3 proj][4 b][128 ptile] = 1536 blocks x 256 thr
// ---------------------------------------------------------------------------
__global__ __launch_bounds__(256, 2) void proj_kernel(
    const float* __restrict__ xq, const float* __restrict__ xk, const float* __restrict__ xv,
    const f16_t* __restrict__ Wall,
    f16_t* __restrict__ qh, f16_t* __restrict__ kh, f16_t* __restrict__ vh)
{
  int bid = blockIdx.x;
  const int pt = bid & 127; bid >>= 7;
  const int b  = bid & 3;   bid >>= 2;
  const int proj = bid;

  const float* X = (proj == 0) ? xq : (proj == 1) ? xk : xv;
  const f16_t* Wf = Wall + (size_t)proj * 131072;
  f16_t* OUT     = (proj == 0) ? qh : (proj == 1) ? kh : vh;

  const int p0 = pt * 128;
  __shared__ __align__(16) f16_t Xl[128 * 256];  // 64 KB

  const int tid = threadIdx.x;
  const int lane = tid & 63, wv = tid >> 6;
  const int wp = (wv & 1) * 64, wo = (wv >> 1) * 64;
  const int l15 = lane & 15, q4 = lane >> 4;

  const size_t xbase = (size_t)b * 256 * 16384;

  // stage X tile [c=256][p=128] fp32 -> LDS [p][k] f16, c-pairs as h2
#pragma unroll
  for (int t = 0; t < 16; ++t) {
    int task = t * 256 + tid;            // 4096 tasks: (c2 128) x (p4 32)
    int c2 = task >> 5, p4 = task & 31;
    int c0 = c2 * 2;
    float4 a0 = *(const float4*)(X + xbase + (size_t)c0 * 16384 + p0 + p4 * 4);
    float4 a1 = *(const float4*)(X + xbase + (size_t)(c0 + 1) * 16384 + p0 + p4 * 4);
    const float* f0 = &a0.x; const float* f1 = &a1.x;
    int g = c0 >> 3;
#pragma unroll
    for (int i = 0; i < 4; ++i) {
      int p = p4 * 4 + i;
      int sw = (p & 7) ^ ((p >> 3) & 7);
      h2 val = (h2){(f16_t)f0[i], (f16_t)f1[i]};
      *(h2*)&Xl[(p << 8) + ((g ^ sw) << 3) + (c0 & 7)] = val;
    }
  }
  __syncthreads();

#pragma unroll 1
  for (int ot = 0; ot < 4; ++ot) {
    f32x4 acc[4][4];
#pragma unroll
    for (int i = 0; i < 4; ++i)
#pragma unroll
      for (int j = 0; j < 4; ++j) acc[i][j] = (f32x4){0.f, 0.f, 0.f, 0.f};

#pragma unroll
    for (int kc = 0; kc < 4; ++kc) {
#pragma unroll
      for (int ks = 0; ks < 2; ++ks) {
        const int gq = kc * 8 + ks * 4 + q4;     // chunk 0..31
        f16x8 af[4], bfr[4];
#pragma unroll
        for (int i = 0; i < 4; ++i) {
          int p = wp + i * 16 + l15;
          int sw = (p & 7) ^ ((p >> 3) & 7);
          int gs = (gq & 0x18) | ((gq ^ sw) & 7);
          af[i] = *(const f16x8*)&Xl[(p << 8) + (gs << 3)];
        }
#pragma unroll
        for (int j = 0; j < 4; ++j) {
          int o = ot * 128 + wo + j * 16 + l15;
          bfr[j] = *(const f16x8*)(Wf + (size_t)o * 256 + kc * 64 + ks * 32 + q4 * 8);
        }
#pragma unroll
        for (int i = 0; i < 4; ++i)
#pragma unroll
          for (int j = 0; j < 4; ++j)
            acc[i][j] = MFMA_F16(af[i], bfr[j], acc[i][j]);
      }
    }

#pragma unroll
    for (int i = 0; i < 4; ++i) {
#pragma unroll
      for (int j = 0; j < 4; ++j) {
        int o = ot * 128 + wo + j * 16 + l15;
        int nn = o >> 6, d = o & 63;
#pragma unroll
        for (int r = 0; r < 4; ++r) {
          int p = p0 + wp + i * 16 + q4 * 4 + r;
          OUT[(((size_t)b * 8 + nn) * 16384 + p) * 64 + d] = (f16_t)acc[i][j][r];
        }
      }
    }
  }
}

// ---------------------------------------------------------------------------
// Stage B: 7x7 local attention, online softmax, dy-paired.
// v6 = v5 + T14 async-STAGE split.  v5 counters: HBM 12%, VALUBusy 37%,
// Occ 21% -> latency-bound; load_row's vmcnt wait sat BEFORE compute.
// Now: per-iter global loads issued into regs at iter top, full compute on
// the other ring slot, ds_write (where vmcnt lands) AFTER compute, then
// barrier.  Staging descriptors (ptr/widx/bounds) are iter-invariant and
// precomputed once.  eA/eB arrays deleted (-14 VGPR): e=exp2(s-m) recomputed
// in the V pass (same exp2 count, identical numerics/order) to keep
// VGPR <= 128 (4 waves/SIMD) with the +21 staging regs.
// grid: [4 b][8 n][16 rowoct][4 wquarter] = 2048 blocks x 256 thr
// ---------------------------------------------------------------------------
__global__ __launch_bounds__(256, 2) void attn_kernel(
    const f16_t* __restrict__ qh, const f16_t* __restrict__ kh,
    const f16_t* __restrict__ vh, f16_t* __restrict__ ao)
{
  int bid = blockIdx.x;
  const int wq = bid & 3;   bid >>= 2;
  const int oc8 = bid & 15; bid >>= 4;
  const int n  = bid & 7;  bid >>= 3;
  const int b  = bid;
  const int h0 = oc8 * 8, w0 = wq * 32;

  const int tid = threadIdx.x;
  const int rp = tid >> 6;          // row-pair 0..3 (wave-uniform)
  const int w  = (tid >> 1) & 31;
  const int dg = tid & 1;           // 32-channel group
  const int dg4 = dg * 4;
  const int hA = h0 + 2 * rp, hB = hA + 1;

  const size_t headoff = ((size_t)b * 8 + n) * 16384 * 64;
  const f16_t* Qh = qh + headoff;
  const f16_t* Kh = kh + headoff;
  const f16_t* Vh = vh + headoff;

  __shared__ uint4 ring[2][38 * 16];  // [slot][pix*16 + (oc ^ (pix&15))]

  union Pack { uint4 u[4]; h2 h[16]; };

  Pack quA, quB;
  {
    const uint4* qa = (const uint4*)(Qh + ((size_t)hA * 128 + w0 + w) * 64 + dg * 32);
    const uint4* qb = (const uint4*)(Qh + ((size_t)hB * 128 + w0 + w) * 64 + dg * 32);
#pragma unroll
    for (int j = 0; j < 4; ++j) { quA.u[j] = qa[j]; quB.u[j] = qb[j]; }
  }

  // ---- iter-invariant staging descriptors (3 tasks/thread, 608 total) ----
  const int task0 = tid, task1 = 256 + tid, task2 = 512 + tid;
  const bool act2 = (task2 < 608);          // tid < 96
  const int pix0 = task0 >> 4, oc0 = task0 & 15;
  const int pix1 = task1 >> 4, oc1 = task1 & 15;
  const int pix2 = task2 >> 4, oc2 = task2 & 15;
  const int ww0 = w0 + pix0 - 3, ww1 = w0 + pix1 - 3, ww2 = w0 + pix2 - 3;
  const bool ok0 = (ww0 >= 0) && (ww0 < 128);
  const bool ok1 = (ww1 >= 0) && (ww1 < 128);
  const bool ok2 = act2 && (ww2 >= 0) && (ww2 < 128);
  const f16_t* sp0 = ((oc0 < 8) ? Kh : Vh) + (ww0 * 64 + (oc0 & 7) * 8);
  const f16_t* sp1 = ((oc1 < 8) ? Kh : Vh) + (ww1 * 64 + (oc1 & 7) * 8);
  const f16_t* sp2 = ((oc2 < 8) ? Kh : Vh) + (ww2 * 64 + (oc2 & 7) * 8);
  const int wi0 = (pix0 << 4) + (oc0 ^ (pix0 & 15));
  const int wi1 = (pix1 << 4) + (oc1 ^ (pix1 & 15));
  const int wi2 = (pix2 << 4) + (oc2 ^ (pix2 & 15));

  const float cscale = 0.18033688011112042f;  // (1/8) * log2(e)

  float mA = -3.0e38f, lA = 0.f, mB = -3.0e38f, lB = 0.f;
  h2 ovA[16], ovB[16];
#pragma unroll
  for (int j = 0; j < 16; ++j) { ovA[j] = (h2){(f16_t)0.f, (f16_t)0.f}; ovB[j] = ovA[j]; }

  // preload first K/V row (h0-3) into slot 0 (direct: load + write)
  {
    const int r = h0 - 3;
    uint4 z = make_uint4(0u, 0u, 0u, 0u);
    uint4 v0 = z, v1 = z, v2 = z;
    if (r >= 0 && r < 128) {
      const size_t roff = (size_t)r * 8192;
      if (ok0) v0 = *(const uint4*)(sp0 + roff);
      if (ok1) v1 = *(const uint4*)(sp1 + roff);
      if (ok2) v2 = *(const uint4*)(sp2 + roff);
    }
    ring[0][wi0] = v0;
    ring[0][wi1] = v1;
    if (act2) ring[0][wi2] = v2;
  }
  __syncthreads();

#pragma unroll 1
  for (int it = 0; it < 14; ++it) {
    // ---- T14 phase 1: issue next-row global loads into regs (no LDS touch) ----
    uint4 rv0 = make_uint4(0u, 0u, 0u, 0u);
    uint4 rv1 = rv0, rv2 = rv0;
    const bool pf = (it < 13);
    {
      const int r = h0 - 2 + it;
      if (pf && r >= 0 && r < 128) {
        const size_t roff = (size_t)r * 8192;
        if (ok0) rv0 = *(const uint4*)(sp0 + roff);
        if (ok1) rv1 = *(const uint4*)(sp1 + roff);
        if (ok2) rv2 = *(const uint4*)(sp2 + roff);
      }
    }

    // ---- compute vs current row ----
    const uint4* cur = ring[it & 1];
    const int dyA = it - 2 * rp;                        // wave-uniform
    const int dyB = dyA - 1;
    const bool aA = (dyA >= 0) && (dyA < 7);
    const bool aB = (dyB >= 0) && (dyB < 7);
    if (aA || aB) {
      // scores vs this k-row for both owned pixels
      float sA[7], sB[7];
#pragma unroll
      for (int dx = 0; dx < 7; ++dx) {
        const int pix = w + dx, sw = pix & 15, base = pix << 4;
        Pack ku;
        ku.u[0] = cur[base + ((dg4 + 0) ^ sw)];
        ku.u[1] = cur[base + ((dg4 + 1) ^ sw)];
        ku.u[2] = cur[base + ((dg4 + 2) ^ sw)];
        ku.u[3] = cur[base + ((dg4 + 3) ^ sw)];
        float accA = 0.f, accB = 0.f;
#pragma unroll
        for (int j = 0; j < 16; ++j) {
          accA = fdot2_(quA.h[j], ku.h[j], accA);
          accB = fdot2_(quB.h[j], ku.h[j], accB);
        }
        sA[dx] = accA; sB[dx] = accB;
      }
#pragma unroll
      for (int dx = 0; dx < 7; ++dx) {
        sA[dx] = (sA[dx] + __shfl_xor(sA[dx], 1)) * cscale;
        sB[dx] = (sB[dx] + __shfl_xor(sB[dx], 1)) * cscale;
      }

      // online softmax: max + rescale only (e recomputed in V pass)
      if (aA) {
        float nm = mA;
#pragma unroll
        for (int dx = 0; dx < 7; ++dx) nm = fmaxf(nm, sA[dx]);
        float alpha = exp2f(mA - nm);
        mA = nm; lA *= alpha;
        f16_t ah = (f16_t)alpha; h2 a2 = (h2){ah, ah};
#pragma unroll
        for (int j = 0; j < 16; ++j) ovA[j] *= a2;
      }
      if (aB) {
        float nm = mB;
#pragma unroll
        for (int dx = 0; dx < 7; ++dx) nm = fmaxf(nm, sB[dx]);
        float alpha = exp2f(mB - nm);
        mB = nm; lB *= alpha;
        f16_t ah = (f16_t)alpha; h2 a2 = (h2){ah, ah};
#pragma unroll
        for (int j = 0; j < 16; ++j) ovB[j] *= a2;
      }

      // weighted V (chunk read shared by both pixels); e computed on the fly
#pragma unroll
      for (int dx = 0; dx < 7; ++dx) {
        const int pix = w + dx, sw = pix & 15, base = pix << 4;
        Pack vu;
        vu.u[0] = cur[base + ((8 + dg4 + 0) ^ sw)];
        vu.u[1] = cur[base + ((8 + dg4 + 1) ^ sw)];
        vu.u[2] = cur[base + ((8 + dg4 + 2) ^ sw)];
        vu.u[3] = cur[base + ((8 + dg4 + 3) ^ sw)];
        if (aA) {
          float e = exp2f(sA[dx] - mA);
          lA += e;
          f16_t eh = (f16_t)e; h2 e2 = (h2){eh, eh};
#pragma unroll
          for (int j = 0; j < 16; ++j) ovA[j] = e2 * vu.h[j] + ovA[j];
        }
        if (aB) {
          float e = exp2f(sB[dx] - mB);
          lB += e;
          f16_t eh = (f16_t)e; h2 e2 = (h2){eh, eh};
#pragma unroll
          for (int j = 0; j < 16; ++j) ovB[j] = e2 * vu.h[j] + ovB[j];
        }
      }
    }

    // ---- T14 phase 2: write staged row to LDS (vmcnt waits land here) ----
    if (pf) {
      uint4* nxt = ring[(it + 1) & 1];
      nxt[wi0] = rv0;
      nxt[wi1] = rv1;
      if (act2) nxt[wi2] = rv2;
    }
    __syncthreads();
  }

  // epilogue: normalize, store 32 f16 channels per owned pixel
  {
    float inv = 1.0f / lA; f16_t ih = (f16_t)inv; h2 i2 = (h2){ih, ih};
    Pack ou;
#pragma unroll
    for (int j = 0; j < 16; ++j) ou.h[j] = ovA[j] * i2;
    uint4* d4 = (uint4*)(ao + (((size_t)b * 16384) + (size_t)hA * 128 + (w0 + w)) * 512 + n * 64 + dg * 32);
    d4[0] = ou.u[0]; d4[1] = ou.u[1]; d4[2] = ou.u[2]; d4[3] = ou.u[3];
  }
  {
    float inv = 1.0f / lB; f16_t ih = (f16_t)inv; h2 i2 = (h2){ih, ih};
    Pack ou;
#pragma unroll
    for (int j = 0; j < 16; ++j) ou.h[j] = ovB[j] * i2;
    uint4* d4 = (uint4*)(ao + (((size_t)b * 16384) + (size_t)hB * 128 + (w0 + w)) * 512 + n * 64 + dg * 32);
    d4[0] = ou.u[0]; d4[1] = ou.u[1]; d4[2] = ou.u[2]; d4[3] = ou.u[3];
  }
}

// ---------------------------------------------------------------------------
// Stage C: o = Wfc @ ao + residual, LayerNorm over C=256, fused.
// ao tile staged ONCE ([p=64][k=512] f16, 64 KB); A-fragments of Wfc_f16
// gathered directly from L2-hot global.  2 barriers/block.
// grid: [4 b][256 ptile(64)] = 1024 blocks x 256 thr
// ---------------------------------------------------------------------------
__global__ __launch_bounds__(256, 2) void fc_ln_kernel(
    const f16_t* __restrict__ ao, const f16_t* __restrict__ Wfc16,
    const float* __restrict__ resid, const float* __restrict__ lnw,
    const float* __restrict__ lnb, float* __restrict__ outp)
{
  int bid = blockIdx.x;
  const int pt = bid & 255;
  const int b = bid >> 8;
  const int p0 = pt * 64;

  const int tid = threadIdx.x;
  const int lane = tid & 63, wv = tid >> 6;
  const int c0w = wv * 64;
  const int l15 = lane & 15, q4 = lane >> 4;

  __shared__ __align__(16) f16_t Bl[64 * 512];  // ao tile [p][k], 64 KB
  __shared__ float lnws[256], lnbs[256];
  __shared__ float red[2][4][64];

  lnws[tid] = lnw[tid];
  lnbs[tid] = lnb[tid];

  // stage full ao tile once
#pragma unroll
  for (int t = 0; t < 16; ++t) {
    int task = t * 256 + tid;            // 4096 tasks: (p 64) x (g 64)
    int p = task >> 6, g = task & 63;
    uint4 v4 = *(const uint4*)(ao + ((size_t)b * 16384 + p0 + p) * 512 + g * 8);
    int gs = (g & 0x38) | ((g ^ (p & 7)) & 7);
    *(uint4*)&Bl[(p << 9) + (gs << 3)] = v4;
  }
  __syncthreads();

  f32x4 acc[4][4];
#pragma unroll
  for (int i = 0; i < 4; ++i)
#pragma unroll
    for (int j = 0; j < 4; ++j) acc[i][j] = (f32x4){0.f, 0.f, 0.f, 0.f};

#pragma unroll 1
  for (int kc = 0; kc < 8; ++kc) {
#pragma unroll
    for (int ks = 0; ks < 2; ++ks) {
      const int gq = kc * 8 + ks * 4 + q4;     // chunk 0..63
      f16x8 af[4], bfr[4];
#pragma unroll
      for (int i = 0; i < 4; ++i) {
        int c = c0w + i * 16 + l15;
        af[i] = *(const f16x8*)(Wfc16 + (size_t)c * 512 + kc * 64 + ks * 32 + q4 * 8);
      }
#pragma unroll
      for (int j = 0; j < 4; ++j) {
        int p = j * 16 + l15;
        int gs = (gq & 0x38) | ((gq ^ (p & 7)) & 7);
        bfr[j] = *(const f16x8*)&Bl[(p << 9) + (gs << 3)];
      }
#pragma unroll
      for (int i = 0; i < 4; ++i)
#pragma unroll
        for (int j = 0; j < 4; ++j)
          acc[i][j] = MFMA_F16(af[i], bfr[j], acc[i][j]);
    }
  }

  float s[4], s2[4];
#pragma unroll
  for (int j = 0; j < 4; ++j) { s[j] = 0.f; s2[j] = 0.f; }
#pragma unroll
  for (int i = 0; i < 4; ++i) {
#pragma unroll
    for (int r = 0; r < 4; ++r) {
      int c = c0w + i * 16 + q4 * 4 + r;
      const float* rp = resid + ((size_t)b * 256 + c) * 16384 + p0;
#pragma unroll
      for (int j = 0; j < 4; ++j) {
        float v = acc[i][j][r] + rp[j * 16 + l15];
        acc[i][j][r] = v;
        s[j] += v; s2[j] += v * v;
      }
    }
  }
#pragma unroll
  for (int j = 0; j < 4; ++j) {
    s[j]  += __shfl_xor(s[j], 16);
    s[j]  += __shfl_xor(s[j], 32);
    s2[j] += __shfl_xor(s2[j], 16);
    s2[j] += __shfl_xor(s2[j], 32);
  }
  if (q4 == 0) {
#pragma unroll
    for (int j = 0; j < 4; ++j) {
      red[0][wv][j * 16 + l15] = s[j];
      red[1][wv][j * 16 + l15] = s2[j];
    }
  }
  __syncthreads();
#pragma unroll
  for (int j = 0; j < 4; ++j) {
    int pl = j * 16 + l15;
    float ts  = red[0][0][pl] + red[0][1][pl] + red[0][2][pl] + red[0][3][pl];
    float ts2 = red[1][0][pl] + red[1][1][pl] + red[1][2][pl] + red[1][3][pl];
    float mean = ts * (1.f / 256.f);
    float var  = ts2 * (1.f / 256.f) - mean * mean;
    float rstd = rsqrtf(var + 1e-6f);
#pragma unroll
    for (int i = 0; i < 4; ++i) {
#pragma unroll
      for (int r = 0; r < 4; ++r) {
        int c = c0w + i * 16 + q4 * 4 + r;
        outp[((size_t)b * 256 + c) * 16384 + p0 + pl] =
            (acc[i][j][r] - mean) * rstd * lnws[c] + lnbs[c];
      }
    }
  }
}

// ---------------------------------------------------------------------------
extern "C" void kernel_launch(void* const* d_in, const int* in_sizes, int n_in,
                              void* d_out, int out_size, void* d_ws, size_t ws_size,
                              hipStream_t stream) {
  const float* q   = (const float*)d_in[0];
  const float* k   = (const float*)d_in[1];
  const float* v   = (const float*)d_in[2];
  const float* Wq  = (const float*)d_in[3];
  const float* Wk  = (const float*)d_in[4];
  const float* Wv  = (const float*)d_in[5];
  const float* Wfc = (const float*)d_in[6];
  const float* lnw = (const float*)d_in[7];
  const float* lnb = (const float*)d_in[8];
  float* outp = (float*)d_out;

  // workspace: 4 x 64 MiB f16 regions; W_f16 copies overlay dead regions:
  //   Wqkv_f16 -> head of ao region (dead until attn rewrites it fully)
  //   Wfc_f16  -> head of qh region (dead after attn)
  f16_t* qh = (f16_t*)d_ws;
  f16_t* kh = qh + 33554432ULL;
  f16_t* vh = kh + 33554432ULL;
  f16_t* ao = vh + 33554432ULL;
  f16_t* Wqkv16 = ao;   // 393216 f16, consumed by proj before attn writes ao
  f16_t* Wfc16  = qh;   // 131072 f16, written after attn, consumed by fc_ln

  wconvA_kernel<<<dim3(384), dim3(256), 0, stream>>>(Wq, Wk, Wv, Wqkv16);
  proj_kernel<<<dim3(1536), dim3(256), 0, stream>>>(q, k, v, Wqkv16, qh, kh, vh);
  attn_kernel<<<dim3(2048), dim3(256), 0, stream>>>(qh, kh, vh, ao);
  wconvB_kernel<<<dim3(128), dim3(256), 0, stream>>>(Wfc, Wfc16);
  fc_ln_kernel<<<dim3(1024), dim3(256), 0, stream>>>(ao, Wfc16, q, lnw, lnb, outp);
}